// Round 23
// baseline (79.299 us; speedup 1.0000x reference)
//
#include <hip/hip_runtime.h>

// Nearest-prototype argmin: N=500k, K=256, D=64, fp32.
// R23 = R22 (autonomous waves, protos as LDS fragments, no in-loop
// barriers, natural VGPR allocation) widened to 32 POINTS/iteration:
// two independent point-groups SHARE one A-fragment/seed LDS stream --
// per-point LDS-read chain halves (R22's suspected ~68us limiter) and the
// two MFMA/pack/shuffle chains interleave (R17 proved the 2-group win).
// Loop/store/ballot paid per 32 points. VGPR ~100 < 128 natural budget
// (R19 precedent: 108 incl. 64 frag regs now moved to LDS). Numerics
// byte-identical per point (absmax=0 heritage R12-R22). Fixup unchanged.

#define DIM 64
#define NPROTO 256
#define NBLK 1024
#define MARGIN_ACC 0.017f

using f32x4 = __attribute__((ext_vector_type(4))) float;
using f16x8 = __attribute__((ext_vector_type(8))) _Float16;

__device__ __forceinline__ f16x8 cvt8(float4 a, float4 b) {
    f16x8 r;
    r[0] = (_Float16)a.x; r[1] = (_Float16)a.y;
    r[2] = (_Float16)a.z; r[3] = (_Float16)a.w;
    r[4] = (_Float16)b.x; r[5] = (_Float16)b.y;
    r[6] = (_Float16)b.z; r[7] = (_Float16)b.w;
    return r;
}

__global__ void __launch_bounds__(256)
argmin_mfma_kernel(const float* __restrict__ X,
                   const float* __restrict__ mus,
                   int* __restrict__ out,
                   unsigned* __restrict__ ws_count,
                   int* __restrict__ ws_list,
                   int use_list, int n) {
    // [p][kt][lane]: lane l's fragment for proto-tile p, K-half kt.
    // Lane-linear 16B chunks -> ds_read_b128 is sequential, conflict-free.
    __shared__ __align__(16) f16x8 s_frag[16][2][64];   // 32 KB
    __shared__ __align__(16) float s_seed[NPROTO];      // -0.5*musq

    const int tid = threadIdx.x;   // 256 = 4 waves
    const int w = tid >> 6;
    const int l = tid & 63;
    const int lp = l & 15;         // A-row / B-col lane index
    const int lg = l >> 4;         // k-group

    // ---- prologue: wave w stages proto-tiles p = w*4 .. w*4+3.
    // Fragment values and musq op order identical to R17 (absmax=0). ----
#pragma unroll
    for (int pp = 0; pp < 4; ++pp) {
        const int p = w * 4 + pp;
        const float* src = mus + (size_t)(p * 16 + lp) * DIM + lg * 8;
        const float4 a = *(const float4*)(src);
        const float4 b = *(const float4*)(src + 4);
        const float4 c = *(const float4*)(src + 32);
        const float4 d = *(const float4*)(src + 36);
        s_frag[p][0][l] = cvt8(a, b);
        s_frag[p][1][l] = cvt8(c, d);
        float s = 0.f;
        s = fmaf(a.x, a.x, fmaf(a.y, a.y, fmaf(a.z, a.z, fmaf(a.w, a.w, s))));
        s = fmaf(b.x, b.x, fmaf(b.y, b.y, fmaf(b.z, b.z, fmaf(b.w, b.w, s))));
        s = fmaf(c.x, c.x, fmaf(c.y, c.y, fmaf(c.z, c.z, fmaf(c.w, c.w, s))));
        s = fmaf(d.x, d.x, fmaf(d.y, d.y, fmaf(d.z, d.z, fmaf(d.w, d.w, s))));
        s += __shfl_xor(s, 16);
        s += __shfl_xor(s, 32);
        if (lg == 0) s_seed[p * 16 + lp] = -0.5f * s;
    }
    __syncthreads();   // the ONLY barrier: publish fragments + seed

    // ---- 32-point group range per GLOBAL wave (autonomous) ----
    const int ngroups = (n + 31) / 32;   // 15625
    const int NW = NBLK * 4;
    const int gwid = blockIdx.x * 4 + w;
    const int q = ngroups / NW, rr = ngroups % NW;
    const int g0 = gwid * q + (gwid < rr ? gwid : rr);
    const int cnt = q + (gwid < rr ? 1 : 0);

    const int kofs = 255 - lg * 4;   // packed value = 255 - kk

    // prefetch group-pair g0: A rows g*32+lp, B rows g*32+16+lp
    float4 xa0, xa1, xa2, xa3, xb0, xb1, xb2, xb3;
    if (cnt > 0) {
        int rA = g0 * 32 + lp;      rA = (rA < n) ? rA : (n - 1);
        int rB = g0 * 32 + 16 + lp; rB = (rB < n) ? rB : (n - 1);
        const float* pA = X + (size_t)rA * DIM + lg * 8;
        const float* pB = X + (size_t)rB * DIM + lg * 8;
        xa0 = *(const float4*)(pA);      xa1 = *(const float4*)(pA + 4);
        xa2 = *(const float4*)(pA + 32); xa3 = *(const float4*)(pA + 36);
        xb0 = *(const float4*)(pB);      xb1 = *(const float4*)(pB + 4);
        xb2 = *(const float4*)(pB + 32); xb3 = *(const float4*)(pB + 36);
    }

    for (int it = 0; it < cnt; ++it) {
        const int g = g0 + it;
        const bool more = (it + 1 < cnt);

        const f16x8 bxA0 = cvt8(xa0, xa1), bxA1 = cvt8(xa2, xa3);
        const f16x8 bxB0 = cvt8(xb0, xb1), bxB1 = cvt8(xb2, xb3);

        // issue next pair's loads; consumed next iteration (no barriers
        // in the loop -> they stay in flight across the whole body)
        if (more) {
            int rA = (g + 1) * 32 + lp;      rA = (rA < n) ? rA : (n - 1);
            int rB = (g + 1) * 32 + 16 + lp; rB = (rB < n) ? rB : (n - 1);
            const float* pA = X + (size_t)rA * DIM + lg * 8;
            const float* pB = X + (size_t)rB * DIM + lg * 8;
            xa0 = *(const float4*)(pA);      xa1 = *(const float4*)(pA + 4);
            xa2 = *(const float4*)(pA + 32); xa3 = *(const float4*)(pA + 36);
            xb0 = *(const float4*)(pB);      xb1 = *(const float4*)(pB + 4);
            xb2 = *(const float4*)(pB + 32); xb3 = *(const float4*)(pB + 36);
        }

        float b1A = -3.4e38f, b2A = -3.4e38f;
        float b1B = -3.4e38f, b2B = -3.4e38f;
#pragma unroll
        for (int p = 0; p < 16; ++p) {
            // one fragment/seed read feeds BOTH groups' MFMA chains
            const f16x8 A0 = s_frag[p][0][l];
            const f16x8 A1 = s_frag[p][1][l];
            const f32x4 seed = *(const f32x4*)&s_seed[p * 16 + lg * 4];
            f32x4 accA = __builtin_amdgcn_mfma_f32_16x16x32_f16(
                A0, bxA0, seed, 0, 0, 0);
            f32x4 accB = __builtin_amdgcn_mfma_f32_16x16x32_f16(
                A0, bxB0, seed, 0, 0, 0);
            accA = __builtin_amdgcn_mfma_f32_16x16x32_f16(A1, bxA1, accA,
                                                          0, 0, 0);
            accB = __builtin_amdgcn_mfma_f32_16x16x32_f16(A1, bxB1, accB,
                                                          0, 0, 0);
            // pack index into low 8 mantissa bits (bits cleared: no carry)
#pragma unroll
            for (int gg = 0; gg < 2; ++gg) {
                const f32x4 acc = gg ? accB : accA;
                float pv[4];
#pragma unroll
                for (int r = 0; r < 4; ++r) {
                    unsigned u = __float_as_uint(acc[r]);
                    u = (u & 0xFFFFFF00u) + (unsigned)(kofs - p * 16 - r);
                    pv[r] = __uint_as_float(u);
                }
                const float t1a = fmaxf(pv[0], pv[1]);
                const float t2a = fminf(pv[0], pv[1]);
                const float t1b = fmaxf(pv[2], pv[3]);
                const float t2b = fminf(pv[2], pv[3]);
                const float p1 = fmaxf(t1a, t1b);
                const float p2 = fmaxf(fminf(t1a, t1b), fmaxf(t2a, t2b));
                if (gg) {
                    const float nb2 = fmaxf(fminf(b1B, p1), fmaxf(b2B, p2));
                    b1B = fmaxf(b1B, p1);
                    b2B = nb2;
                } else {
                    const float nb2 = fmaxf(fminf(b1A, p1), fmaxf(b2A, p2));
                    b1A = fmaxf(b1A, p1);
                    b2A = nb2;
                }
            }
        }
        // cross-lane over lg; two independent butterflies interleave
#pragma unroll
        for (int m = 16; m <= 32; m <<= 1) {
            const float o1A = __shfl_xor(b1A, m), o2A = __shfl_xor(b2A, m);
            const float o1B = __shfl_xor(b1B, m), o2B = __shfl_xor(b2B, m);
            const float n2A = fmaxf(fminf(b1A, o1A), fmaxf(b2A, o2A));
            const float n2B = fmaxf(fminf(b1B, o1B), fmaxf(b2B, o2B));
            b1A = fmaxf(b1A, o1A); b2A = n2A;
            b1B = fmaxf(b1B, o1B); b2B = n2B;
        }

        // store: lane l<16 -> group A point g*32+l (lp=l); lanes 16..31 ->
        // group B point g*32+l (lp=l-16). All lg copies agree post-butterfly.
        bool fl = false;
        const int i = g * 32 + l;   // valid for l < 32
        if (l < 32 && i < n) {
            const float f1 = (l < 16) ? b1A : b1B;
            const float f2 = (l < 16) ? b2A : b2B;
            const unsigned u1 = __float_as_uint(f1);
            const int k1 = 255 - (int)(u1 & 0xFFu);
            const float v1 = __uint_as_float(u1 & 0xFFFFFF00u);
            const float v2 =
                __uint_as_float(__float_as_uint(f2) & 0xFFFFFF00u);
            const bool close = (v1 - v2) < MARGIN_ACC;
            if (use_list) {
                out[i] = k1;
                fl = close;
            } else {
                out[i] = (int)((unsigned)k1 | (close ? 0x80000000u : 0u));
            }
        }
        if (use_list) {
            const unsigned long long mask = __ballot(fl);
            if (mask) {
                unsigned base = 0;
                if (l == 0)
                    base = atomicAdd(ws_count, (unsigned)__popcll(mask));
                base = __shfl(base, 0);
                if (fl)
                    ws_list[base + __popcll(mask & ((1ull << l) - 1))] = i;
            }
        }
    }
}

#define MSTRIDE 65   // padded row stride: bank (l+d)%32, 2 lanes/bank = free

// LDS-staged exact-fp32 fixup over the compacted list (R13-proven).
__global__ void __launch_bounds__(256)
fixup_lds_kernel(const float* __restrict__ X, const float* __restrict__ mus,
                 const unsigned* __restrict__ ws_count,
                 const int* __restrict__ ws_list, int* __restrict__ out) {
    __shared__ float s_mu[NPROTO * MSTRIDE];  // 65 KB
    __shared__ float s_msq[NPROTO];

    const int tid = threadIdx.x;
    {
        const float4* mr = (const float4*)(mus + (size_t)tid * DIM);
        float q0 = 0.f, q1 = 0.f, q2 = 0.f, q3 = 0.f;
#pragma unroll
        for (int qq = 0; qq < 16; ++qq) {
            const float4 mv = mr[qq];
            const int base = tid * MSTRIDE + qq * 4;
            s_mu[base]     = mv.x;
            s_mu[base + 1] = mv.y;
            s_mu[base + 2] = mv.z;
            s_mu[base + 3] = mv.w;
            q0 = fmaf(mv.x, mv.x, q0);
            q1 = fmaf(mv.y, mv.y, q1);
            q2 = fmaf(mv.z, mv.z, q2);
            q3 = fmaf(mv.w, mv.w, q3);
        }
        s_msq[tid] = (q0 + q1) + (q2 + q3);
    }
    __syncthreads();

    const int l = tid & 63;
    const int gw = (int)((blockIdx.x * blockDim.x + tid) >> 6);
    const int NW = (int)((gridDim.x * blockDim.x) >> 6);
    const int nf = (int)*ws_count;

    for (int j = gw; j < nf; j += NW) {
        const int pt = ws_list[j];
        const float4* xr = (const float4*)(X + (size_t)pt * DIM);
        float4 xv[16];
        float a0 = 0.f, a1 = 0.f, a2 = 0.f, a3 = 0.f;
#pragma unroll
        for (int qq = 0; qq < 16; ++qq) {
            xv[qq] = xr[qq];
            a0 = fmaf(xv[qq].x, xv[qq].x, a0);
            a1 = fmaf(xv[qq].y, xv[qq].y, a1);
            a2 = fmaf(xv[qq].z, xv[qq].z, a2);
            a3 = fmaf(xv[qq].w, xv[qq].w, a3);
        }
        const float xsq = (a0 + a1) + (a2 + a3);
        float b1 = 3.4e38f;
        int k1 = 0;
#pragma unroll
        for (int e = 0; e < 4; ++e) {
            const int p = e * 64 + l;           // k ascending per lane
            const float* mr = &s_mu[p * MSTRIDE];
            float d0 = 0.f, d1 = 0.f, d2 = 0.f, d3 = 0.f;
#pragma unroll
            for (int qq = 0; qq < 16; ++qq) {
                d0 = fmaf(mr[qq * 4],     xv[qq].x, d0);
                d1 = fmaf(mr[qq * 4 + 1], xv[qq].y, d1);
                d2 = fmaf(mr[qq * 4 + 2], xv[qq].z, d2);
                d3 = fmaf(mr[qq * 4 + 3], xv[qq].w, d3);
            }
            const float dot = (d0 + d1) + (d2 + d3);
            const float dd = (xsq - 2.0f * dot) + s_msq[p];
            if (dd < b1) { b1 = dd; k1 = p; }   // strict <: first-min
        }
#pragma unroll
        for (int mm = 1; mm < 64; mm <<= 1) {
            const float ob = __shfl_xor(b1, mm);
            const int ok = __shfl_xor(k1, mm);
            if (ob < b1 || (ob == b1 && ok < k1)) { b1 = ob; k1 = ok; }
        }
        if (l == 0) out[pt] = k1;
    }
}

// Fallback scan fixup with LDS-staged mus (used only if ws too small).
__global__ void __launch_bounds__(256)
fixup_scan_lds_kernel(const float* __restrict__ X,
                      const float* __restrict__ mus,
                      int* __restrict__ out, int n) {
    __shared__ float s_mu[NPROTO * MSTRIDE];  // 65 KB
    __shared__ float s_msq[NPROTO];

    const int tid = threadIdx.x;
    {
        const float4* mr = (const float4*)(mus + (size_t)tid * DIM);
        float q0 = 0.f, q1 = 0.f, q2 = 0.f, q3 = 0.f;
#pragma unroll
        for (int qq = 0; qq < 16; ++qq) {
            const float4 mv = mr[qq];
            const int base = tid * MSTRIDE + qq * 4;
            s_mu[base]     = mv.x;
            s_mu[base + 1] = mv.y;
            s_mu[base + 2] = mv.z;
            s_mu[base + 3] = mv.w;
            q0 = fmaf(mv.x, mv.x, q0);
            q1 = fmaf(mv.y, mv.y, q1);
            q2 = fmaf(mv.z, mv.z, q2);
            q3 = fmaf(mv.w, mv.w, q3);
        }
        s_msq[tid] = (q0 + q1) + (q2 + q3);
    }
    __syncthreads();

    const int l = tid & 63;
    const int gw = (int)((blockIdx.x * blockDim.x + tid) >> 6);
    const int NW = (int)((gridDim.x * blockDim.x) >> 6);
    const int chunk = (n + NW - 1) / NW;
    const int base = gw * chunk;
    const int end = (base + chunk < n) ? (base + chunk) : n;

    for (int s = base; s < end; s += 64) {
        const int i = s + l;
        const int v = (i < end) ? out[i] : 0;
        const bool flg = (i < end) && ((unsigned)v & 0x80000000u);
        unsigned long long m = __ballot(flg);
        while (m) {
            const int src = (int)__ffsll((unsigned long long)m) - 1;
            m &= m - 1;
            const int pt = __shfl(i, src);
            const float4* xr = (const float4*)(X + (size_t)pt * DIM);
            float4 xv[16];
            float a0 = 0.f, a1 = 0.f, a2 = 0.f, a3 = 0.f;
#pragma unroll
            for (int qq = 0; qq < 16; ++qq) {
                xv[qq] = xr[qq];
                a0 = fmaf(xv[qq].x, xv[qq].x, a0);
                a1 = fmaf(xv[qq].y, xv[qq].y, a1);
                a2 = fmaf(xv[qq].z, xv[qq].z, a2);
                a3 = fmaf(xv[qq].w, xv[qq].w, a3);
            }
            const float xsq = (a0 + a1) + (a2 + a3);
            float b1 = 3.4e38f;
            int k1 = 0;
#pragma unroll
            for (int e = 0; e < 4; ++e) {
                const int p = e * 64 + l;
                const float* mr = &s_mu[p * MSTRIDE];
                float d0 = 0.f, d1 = 0.f, d2 = 0.f, d3 = 0.f;
#pragma unroll
                for (int qq = 0; qq < 16; ++qq) {
                    d0 = fmaf(mr[qq * 4],     xv[qq].x, d0);
                    d1 = fmaf(mr[qq * 4 + 1], xv[qq].y, d1);
                    d2 = fmaf(mr[qq * 4 + 2], xv[qq].z, d2);
                    d3 = fmaf(mr[qq * 4 + 3], xv[qq].w, d3);
                }
                const float dot = (d0 + d1) + (d2 + d3);
                const float dd = (xsq - 2.0f * dot) + s_msq[p];
                if (dd < b1) { b1 = dd; k1 = p; }
            }
#pragma unroll
            for (int mm = 1; mm < 64; mm <<= 1) {
                const float ob = __shfl_xor(b1, mm);
                const int ok = __shfl_xor(k1, mm);
                if (ob < b1 || (ob == b1 && ok < k1)) { b1 = ob; k1 = ok; }
            }
            if (l == 0) out[pt] = k1;
        }
    }
}

extern "C" void kernel_launch(void* const* d_in, const int* in_sizes, int n_in,
                              void* d_out, int out_size, void* d_ws, size_t ws_size,
                              hipStream_t stream) {
    const float* X = (const float*)d_in[0];
    const float* mus = (const float*)d_in[1];
    int* out = (int*)d_out;
    const int n = in_sizes[0] / DIM;  // 500000

    unsigned* ws_count = (unsigned*)d_ws;
    int* ws_list = (int*)((char*)d_ws + 16);
    const int use_list = (ws_size >= 16 + (size_t)n * 4) ? 1 : 0;

    if (use_list) {
        hipMemsetAsync(d_ws, 0, 16, stream);  // reset append counter
    }

    argmin_mfma_kernel<<<NBLK, 256, 0, stream>>>(X, mus, out, ws_count,
                                                 ws_list, use_list, n);
    if (use_list) {
        fixup_lds_kernel<<<512, 256, 0, stream>>>(X, mus, ws_count, ws_list,
                                                  out);
    } else {
        fixup_scan_lds_kernel<<<512, 256, 0, stream>>>(X, mus, out, n);
    }
}

// Round 24
// 76.573 us; speedup vs baseline: 1.0356x; 1.0356x over previous
//
#include <hip/hip_runtime.h>

// Nearest-prototype argmin: N=500k, K=256, D=64, fp32.
// R24 = R22 (autonomous waves, protos as LDS fragments, no in-loop
// barriers, natural VGPR allocation — best measured, 76.3us) with the
// SEEDS HOISTED TO REGISTERS: mh[16] (f32x4, 64 VGPR) loaded once after
// the one-time barrier. Removes the per-p ds_read(seed)->lgkmcnt->MFMA
// C-operand dependency that serialized the 16 p-steps (the last
// un-attacked serial chain; R23 falsified LDS-BW, R14/15/18/22 falsified
// waves/barriers/atomics). R12 proved register-seed MFMA C numerics
// (absmax=0). Everything else byte-identical to R22.

#define DIM 64
#define NPROTO 256
#define NBLK 1024
#define MARGIN_ACC 0.017f

using f32x4 = __attribute__((ext_vector_type(4))) float;
using f16x8 = __attribute__((ext_vector_type(8))) _Float16;

__device__ __forceinline__ f16x8 cvt8(float4 a, float4 b) {
    f16x8 r;
    r[0] = (_Float16)a.x; r[1] = (_Float16)a.y;
    r[2] = (_Float16)a.z; r[3] = (_Float16)a.w;
    r[4] = (_Float16)b.x; r[5] = (_Float16)b.y;
    r[6] = (_Float16)b.z; r[7] = (_Float16)b.w;
    return r;
}

__global__ void __launch_bounds__(256)
argmin_mfma_kernel(const float* __restrict__ X,
                   const float* __restrict__ mus,
                   int* __restrict__ out,
                   unsigned* __restrict__ ws_count,
                   int* __restrict__ ws_list,
                   int use_list, int n) {
    // [p][kt][lane]: lane l's fragment for proto-tile p, K-half kt.
    // Lane-linear 16B chunks -> ds_read_b128 is sequential, conflict-free.
    __shared__ __align__(16) f16x8 s_frag[16][2][64];   // 32 KB
    __shared__ __align__(16) float s_seed[NPROTO];      // -0.5*musq

    const int tid = threadIdx.x;   // 256 = 4 waves
    const int w = tid >> 6;
    const int l = tid & 63;
    const int lp = l & 15;         // A-row / B-col lane index
    const int lg = l >> 4;         // k-group

    // ---- prologue: wave w stages proto-tiles p = w*4 .. w*4+3.
    // Fragment values and musq op order identical to R17 (absmax=0). ----
#pragma unroll
    for (int pp = 0; pp < 4; ++pp) {
        const int p = w * 4 + pp;
        const float* src = mus + (size_t)(p * 16 + lp) * DIM + lg * 8;
        const float4 a = *(const float4*)(src);
        const float4 b = *(const float4*)(src + 4);
        const float4 c = *(const float4*)(src + 32);
        const float4 d = *(const float4*)(src + 36);
        s_frag[p][0][l] = cvt8(a, b);
        s_frag[p][1][l] = cvt8(c, d);
        float s = 0.f;
        s = fmaf(a.x, a.x, fmaf(a.y, a.y, fmaf(a.z, a.z, fmaf(a.w, a.w, s))));
        s = fmaf(b.x, b.x, fmaf(b.y, b.y, fmaf(b.z, b.z, fmaf(b.w, b.w, s))));
        s = fmaf(c.x, c.x, fmaf(c.y, c.y, fmaf(c.z, c.z, fmaf(c.w, c.w, s))));
        s = fmaf(d.x, d.x, fmaf(d.y, d.y, fmaf(d.z, d.z, fmaf(d.w, d.w, s))));
        s += __shfl_xor(s, 16);
        s += __shfl_xor(s, 32);
        if (lg == 0) s_seed[p * 16 + lp] = -0.5f * s;
    }
    __syncthreads();   // the ONLY barrier: publish fragments + seed

    // seeds -> registers, held across ALL iterations (iteration-invariant;
    // kills the per-p ds_read->MFMA C-operand chain). 64 VGPR.
    f32x4 mh[16];
#pragma unroll
    for (int p = 0; p < 16; ++p)
        mh[p] = *(const f32x4*)&s_seed[p * 16 + lg * 4];

    // ---- 16-point group range per GLOBAL wave (autonomous) ----
    const int ngroups = (n + 15) / 16;   // 31250
    const int NW = NBLK * 4;
    const int gwid = blockIdx.x * 4 + w;
    const int q = ngroups / NW, rr = ngroups % NW;
    const int g0 = gwid * q + (gwid < rr ? gwid : rr);
    const int cnt = q + (gwid < rr ? 1 : 0);

    const int kofs = 255 - lg * 4;   // packed value = 255 - kk

    // prefetch group g0 (lane: row g*16+lp, dims lg*8 + kt*32)
    float4 xr0, xr1, xr2, xr3;
    if (cnt > 0) {
        int row = g0 * 16 + lp; row = (row < n) ? row : (n - 1);
        const float* rp = X + (size_t)row * DIM + lg * 8;
        xr0 = *(const float4*)(rp);
        xr1 = *(const float4*)(rp + 4);
        xr2 = *(const float4*)(rp + 32);
        xr3 = *(const float4*)(rp + 36);
    }

    for (int it = 0; it < cnt; ++it) {
        const int g = g0 + it;
        const bool more = (it + 1 < cnt);

        const f16x8 bx0 = cvt8(xr0, xr1);
        const f16x8 bx1 = cvt8(xr2, xr3);

        // issue next group's loads; consumed next iteration (no barriers
        // in the loop -> they stay in flight across the whole body)
        if (more) {
            int row = (g + 1) * 16 + lp; row = (row < n) ? row : (n - 1);
            const float* rp = X + (size_t)row * DIM + lg * 8;
            xr0 = *(const float4*)(rp);
            xr1 = *(const float4*)(rp + 4);
            xr2 = *(const float4*)(rp + 32);
            xr3 = *(const float4*)(rp + 36);
        }

        float b1 = -3.4e38f, b2 = -3.4e38f;
#pragma unroll
        for (int p = 0; p < 16; ++p) {
            // A-frags from LDS; seed already in registers -> the MFMA can
            // fire as soon as A0 lands (no per-p seed read chain)
            const f16x8 A0 = s_frag[p][0][l];
            const f16x8 A1 = s_frag[p][1][l];
            f32x4 acc = __builtin_amdgcn_mfma_f32_16x16x32_f16(
                A0, bx0, mh[p], 0, 0, 0);
            acc = __builtin_amdgcn_mfma_f32_16x16x32_f16(A1, bx1, acc,
                                                         0, 0, 0);
            // pack index into low 8 mantissa bits (bits cleared: no carry)
            float pv[4];
#pragma unroll
            for (int r = 0; r < 4; ++r) {
                unsigned u = __float_as_uint(acc[r]);
                u = (u & 0xFFFFFF00u) + (unsigned)(kofs - p * 16 - r);
                pv[r] = __uint_as_float(u);
            }
            const float t1a = fmaxf(pv[0], pv[1]), t2a = fminf(pv[0], pv[1]);
            const float t1b = fmaxf(pv[2], pv[3]), t2b = fminf(pv[2], pv[3]);
            const float p1 = fmaxf(t1a, t1b);
            const float p2 = fmaxf(fminf(t1a, t1b), fmaxf(t2a, t2b));
            const float nb2 = fmaxf(fminf(b1, p1), fmaxf(b2, p2));
            b1 = fmaxf(b1, p1);
            b2 = nb2;
        }
        // cross-lane over lg (4 lanes share point lp)
#pragma unroll
        for (int m = 16; m <= 32; m <<= 1) {
            const float o1 = __shfl_xor(b1, m);
            const float o2 = __shfl_xor(b2, m);
            const float nb2 = fmaxf(fminf(b1, o1), fmaxf(b2, o2));
            b1 = fmaxf(b1, o1);
            b2 = nb2;
        }

        bool fl = false;
        const int i = g * 16 + l;   // valid for l < 16
        if (l < 16 && i < n) {
            const unsigned u1 = __float_as_uint(b1);
            const int k1 = 255 - (int)(u1 & 0xFFu);
            const float v1 = __uint_as_float(u1 & 0xFFFFFF00u);
            const float v2 =
                __uint_as_float(__float_as_uint(b2) & 0xFFFFFF00u);
            const bool close = (v1 - v2) < MARGIN_ACC;
            if (use_list) {
                out[i] = k1;
                fl = close;
            } else {
                out[i] = (int)((unsigned)k1 | (close ? 0x80000000u : 0u));
            }
        }
        if (use_list) {
            const unsigned long long mask = __ballot(fl);
            if (mask) {
                unsigned base = 0;
                if (l == 0)
                    base = atomicAdd(ws_count, (unsigned)__popcll(mask));
                base = __shfl(base, 0);
                if (fl)
                    ws_list[base + __popcll(mask & ((1ull << l) - 1))] = i;
            }
        }
    }
}

#define MSTRIDE 65   // padded row stride: bank (l+d)%32, 2 lanes/bank = free

// LDS-staged exact-fp32 fixup over the compacted list (R13-proven).
__global__ void __launch_bounds__(256)
fixup_lds_kernel(const float* __restrict__ X, const float* __restrict__ mus,
                 const unsigned* __restrict__ ws_count,
                 const int* __restrict__ ws_list, int* __restrict__ out) {
    __shared__ float s_mu[NPROTO * MSTRIDE];  // 65 KB
    __shared__ float s_msq[NPROTO];

    const int tid = threadIdx.x;
    {
        const float4* mr = (const float4*)(mus + (size_t)tid * DIM);
        float q0 = 0.f, q1 = 0.f, q2 = 0.f, q3 = 0.f;
#pragma unroll
        for (int qq = 0; qq < 16; ++qq) {
            const float4 mv = mr[qq];
            const int base = tid * MSTRIDE + qq * 4;
            s_mu[base]     = mv.x;
            s_mu[base + 1] = mv.y;
            s_mu[base + 2] = mv.z;
            s_mu[base + 3] = mv.w;
            q0 = fmaf(mv.x, mv.x, q0);
            q1 = fmaf(mv.y, mv.y, q1);
            q2 = fmaf(mv.z, mv.z, q2);
            q3 = fmaf(mv.w, mv.w, q3);
        }
        s_msq[tid] = (q0 + q1) + (q2 + q3);
    }
    __syncthreads();

    const int l = tid & 63;
    const int gw = (int)((blockIdx.x * blockDim.x + tid) >> 6);
    const int NW = (int)((gridDim.x * blockDim.x) >> 6);
    const int nf = (int)*ws_count;

    for (int j = gw; j < nf; j += NW) {
        const int pt = ws_list[j];
        const float4* xr = (const float4*)(X + (size_t)pt * DIM);
        float4 xv[16];
        float a0 = 0.f, a1 = 0.f, a2 = 0.f, a3 = 0.f;
#pragma unroll
        for (int qq = 0; qq < 16; ++qq) {
            xv[qq] = xr[qq];
            a0 = fmaf(xv[qq].x, xv[qq].x, a0);
            a1 = fmaf(xv[qq].y, xv[qq].y, a1);
            a2 = fmaf(xv[qq].z, xv[qq].z, a2);
            a3 = fmaf(xv[qq].w, xv[qq].w, a3);
        }
        const float xsq = (a0 + a1) + (a2 + a3);
        float b1 = 3.4e38f;
        int k1 = 0;
#pragma unroll
        for (int e = 0; e < 4; ++e) {
            const int p = e * 64 + l;           // k ascending per lane
            const float* mr = &s_mu[p * MSTRIDE];
            float d0 = 0.f, d1 = 0.f, d2 = 0.f, d3 = 0.f;
#pragma unroll
            for (int qq = 0; qq < 16; ++qq) {
                d0 = fmaf(mr[qq * 4],     xv[qq].x, d0);
                d1 = fmaf(mr[qq * 4 + 1], xv[qq].y, d1);
                d2 = fmaf(mr[qq * 4 + 2], xv[qq].z, d2);
                d3 = fmaf(mr[qq * 4 + 3], xv[qq].w, d3);
            }
            const float dot = (d0 + d1) + (d2 + d3);
            const float dd = (xsq - 2.0f * dot) + s_msq[p];
            if (dd < b1) { b1 = dd; k1 = p; }   // strict <: first-min
        }
#pragma unroll
        for (int mm = 1; mm < 64; mm <<= 1) {
            const float ob = __shfl_xor(b1, mm);
            const int ok = __shfl_xor(k1, mm);
            if (ob < b1 || (ob == b1 && ok < k1)) { b1 = ob; k1 = ok; }
        }
        if (l == 0) out[pt] = k1;
    }
}

// Fallback scan fixup with LDS-staged mus (used only if ws too small).
__global__ void __launch_bounds__(256)
fixup_scan_lds_kernel(const float* __restrict__ X,
                      const float* __restrict__ mus,
                      int* __restrict__ out, int n) {
    __shared__ float s_mu[NPROTO * MSTRIDE];  // 65 KB
    __shared__ float s_msq[NPROTO];

    const int tid = threadIdx.x;
    {
        const float4* mr = (const float4*)(mus + (size_t)tid * DIM);
        float q0 = 0.f, q1 = 0.f, q2 = 0.f, q3 = 0.f;
#pragma unroll
        for (int qq = 0; qq < 16; ++qq) {
            const float4 mv = mr[qq];
            const int base = tid * MSTRIDE + qq * 4;
            s_mu[base]     = mv.x;
            s_mu[base + 1] = mv.y;
            s_mu[base + 2] = mv.z;
            s_mu[base + 3] = mv.w;
            q0 = fmaf(mv.x, mv.x, q0);
            q1 = fmaf(mv.y, mv.y, q1);
            q2 = fmaf(mv.z, mv.z, q2);
            q3 = fmaf(mv.w, mv.w, q3);
        }
        s_msq[tid] = (q0 + q1) + (q2 + q3);
    }
    __syncthreads();

    const int l = tid & 63;
    const int gw = (int)((blockIdx.x * blockDim.x + tid) >> 6);
    const int NW = (int)((gridDim.x * blockDim.x) >> 6);
    const int chunk = (n + NW - 1) / NW;
    const int base = gw * chunk;
    const int end = (base + chunk < n) ? (base + chunk) : n;

    for (int s = base; s < end; s += 64) {
        const int i = s + l;
        const int v = (i < end) ? out[i] : 0;
        const bool flg = (i < end) && ((unsigned)v & 0x80000000u);
        unsigned long long m = __ballot(flg);
        while (m) {
            const int src = (int)__ffsll((unsigned long long)m) - 1;
            m &= m - 1;
            const int pt = __shfl(i, src);
            const float4* xr = (const float4*)(X + (size_t)pt * DIM);
            float4 xv[16];
            float a0 = 0.f, a1 = 0.f, a2 = 0.f, a3 = 0.f;
#pragma unroll
            for (int qq = 0; qq < 16; ++qq) {
                xv[qq] = xr[qq];
                a0 = fmaf(xv[qq].x, xv[qq].x, a0);
                a1 = fmaf(xv[qq].y, xv[qq].y, a1);
                a2 = fmaf(xv[qq].z, xv[qq].z, a2);
                a3 = fmaf(xv[qq].w, xv[qq].w, a3);
            }
            const float xsq = (a0 + a1) + (a2 + a3);
            float b1 = 3.4e38f;
            int k1 = 0;
#pragma unroll
            for (int e = 0; e < 4; ++e) {
                const int p = e * 64 + l;
                const float* mr = &s_mu[p * MSTRIDE];
                float d0 = 0.f, d1 = 0.f, d2 = 0.f, d3 = 0.f;
#pragma unroll
                for (int qq = 0; qq < 16; ++qq) {
                    d0 = fmaf(mr[qq * 4],     xv[qq].x, d0);
                    d1 = fmaf(mr[qq * 4 + 1], xv[qq].y, d1);
                    d2 = fmaf(mr[qq * 4 + 2], xv[qq].z, d2);
                    d3 = fmaf(mr[qq * 4 + 3], xv[qq].w, d3);
                }
                const float dot = (d0 + d1) + (d2 + d3);
                const float dd = (xsq - 2.0f * dot) + s_msq[p];
                if (dd < b1) { b1 = dd; k1 = p; }
            }
#pragma unroll
            for (int mm = 1; mm < 64; mm <<= 1) {
                const float ob = __shfl_xor(b1, mm);
                const int ok = __shfl_xor(k1, mm);
                if (ob < b1 || (ob == b1 && ok < k1)) { b1 = ob; k1 = ok; }
            }
            if (l == 0) out[pt] = k1;
        }
    }
}

extern "C" void kernel_launch(void* const* d_in, const int* in_sizes, int n_in,
                              void* d_out, int out_size, void* d_ws, size_t ws_size,
                              hipStream_t stream) {
    const float* X = (const float*)d_in[0];
    const float* mus = (const float*)d_in[1];
    int* out = (int*)d_out;
    const int n = in_sizes[0] / DIM;  // 500000

    unsigned* ws_count = (unsigned*)d_ws;
    int* ws_list = (int*)((char*)d_ws + 16);
    const int use_list = (ws_size >= 16 + (size_t)n * 4) ? 1 : 0;

    if (use_list) {
        hipMemsetAsync(d_ws, 0, 16, stream);  // reset append counter
    }

    argmin_mfma_kernel<<<NBLK, 256, 0, stream>>>(X, mus, out, ws_count,
                                                 ws_list, use_list, n);
    if (use_list) {
        fixup_lds_kernel<<<512, 256, 0, stream>>>(X, mus, ws_count, ws_list,
                                                  out);
    } else {
        fixup_scan_lds_kernel<<<512, 256, 0, stream>>>(X, mus, out, n);
    }
}